// Round 6
// baseline (904.066 us; speedup 1.0000x reference)
//
#include <hip/hip_runtime.h>
#include <hip/hip_cooperative_groups.h>

namespace cg = cooperative_groups;

#define N_NODES 50000
#define N_EDGES 800000
#define BATCH   32
#define NWORD8  12500   // N_NODES/4 u32 words (u8-packed deg counts / qd8 table)
#define NWORDC  25000   // N_NODES/2 u32 words, u16-packed c (full range, 100 KB)
#define CHUNKS  8       // 256 blocks = 32 batches x 8 chunks, 1 block/CU
#define EPC4    25000   // int4 loads per chunk (= 100000 edges)
#define NODESPC 6250    // nodes per chunk in phase D (pool)
#define QSCALE  255.0f
#define SMEM_WORDS 37500  // 150 KB: max over phases (C needs NWORDC+NWORD8)

// ---------------------------------------------------------------------------
// Single cooperative kernel, 5 phases separated by grid.sync():
//  A: per-(b,chunk) degree histogram (u8x4 packed LDS) -> hpart (12.8 MB)
//  B: reduce hpart -> dinv (f32) + qd8 (u8 packed)
//  C: c-scatter: u16-packed full-range LDS histogram; dst-dinv gathered from
//     a 50 KB LDS u8 table (R3 lesson: divergent global gathers are ~6x worse)
//  D: w = dinv*(c+dinv) computed INTO LDS (never global), then coalesced
//     float4 pool of xg against LDS w -> spart   (w round-trip eliminated)
//  E: block 0: tiny MLP + log_softmax(axis=0)
// 1 block/CU (150 KB LDS) — phases A/C are VMEM+LDS-atomic bound at 16 waves.
// ---------------------------------------------------------------------------
__global__ __launch_bounds__(1024) void mega_kernel(
    const float* __restrict__ x, const float* __restrict__ gcn_x,
    const int* __restrict__ ei,
    const float* __restrict__ W_gcn, const float* __restrict__ b_gcn,
    const float* __restrict__ W1, const float* __restrict__ b1,
    const float* __restrict__ W2, const float* __restrict__ b2,
    const float* __restrict__ Wo, const float* __restrict__ bo,
    float* __restrict__ out,
    unsigned* __restrict__ hpart,   // [32][8][NWORD8]
    unsigned* __restrict__ cpart,   // [32][8][NWORDC]
    float* __restrict__ dinv,       // [32][N_NODES]
    unsigned* __restrict__ qd8,     // [32][NWORD8]
    float* __restrict__ spart)      // [32][8][16]
{
    extern __shared__ unsigned smem[];
    cg::grid_group grid = cg::this_grid();
    const int tid = threadIdx.x;
    const int id = blockIdx.x;
    // swizzle: batch spread across XCDs (id%8 = XCD), chunk slow
    const int b = (id & 7) + 8 * ((id >> 3) & 3);
    const int chunk = id >> 5;
    const int* eb = ei + (size_t)b * (2 * N_EDGES);

    // ---------------- Phase A: degree histogram ----------------
    for (int i = tid; i < NWORD8; i += 1024) smem[i] = 0;
    __syncthreads();
    {
        const int4* __restrict__ dst4 = (const int4*)(eb + N_EDGES) + (size_t)chunk * EPC4;
        for (int i = tid; i < EPC4; i += 1024) {
            const int4 v = dst4[i];
            atomicAdd(&smem[((unsigned)v.x) >> 2], 1u << ((v.x & 3) * 8));
            atomicAdd(&smem[((unsigned)v.y) >> 2], 1u << ((v.y & 3) * 8));
            atomicAdd(&smem[((unsigned)v.z) >> 2], 1u << ((v.z & 3) * 8));
            atomicAdd(&smem[((unsigned)v.w) >> 2], 1u << ((v.w & 3) * 8));
        }
    }
    __syncthreads();
    {
        unsigned* __restrict__ o = hpart + (size_t)(b * CHUNKS + chunk) * NWORD8;
        for (int i = tid; i < NWORD8; i += 1024) o[i] = smem[i];
    }
    __threadfence();
    grid.sync();

    // ---------------- Phase B: dinv + qd8 ----------------
    for (int idx = id * 1024 + tid; idx < BATCH * NWORD8; idx += 256 * 1024) {
        const int bb = idx / NWORD8, i = idx - bb * NWORD8;
        const unsigned* __restrict__ p = hpart + (size_t)(bb * CHUNKS) * NWORD8 + i;
        unsigned d0 = 0, d1 = 0, d2 = 0, d3 = 0;
#pragma unroll
        for (int c = 0; c < CHUNKS; ++c) {
            const unsigned v = p[(size_t)c * NWORD8];
            d0 += v & 0xFF; d1 += (v >> 8) & 0xFF; d2 += (v >> 16) & 0xFF; d3 += v >> 24;
        }
        const float i0 = rsqrtf((float)(d0 + 1));
        const float i1 = rsqrtf((float)(d1 + 1));
        const float i2 = rsqrtf((float)(d2 + 1));
        const float i3 = rsqrtf((float)(d3 + 1));
        float4* dv4 = (float4*)(dinv + (size_t)bb * N_NODES) + i;
        *dv4 = make_float4(i0, i1, i2, i3);
        const unsigned q0 = __float2uint_rn(i0 * QSCALE);
        const unsigned q1 = __float2uint_rn(i1 * QSCALE);
        const unsigned q2 = __float2uint_rn(i2 * QSCALE);
        const unsigned q3 = __float2uint_rn(i3 * QSCALE);
        qd8[(size_t)bb * NWORD8 + i] = q0 | (q1 << 8) | (q2 << 16) | (q3 << 24);
    }
    __threadfence();
    grid.sync();

    // ---------------- Phase C: c-scatter ----------------
    {
        unsigned* cs = smem;
        const unsigned char* qs = (const unsigned char*)(smem + NWORDC);
        for (int i = tid; i < NWORDC; i += 1024) cs[i] = 0;
        {   // stage this batch's u8 dinv table (50 KB, coalesced)
            const unsigned* __restrict__ src = qd8 + (size_t)b * NWORD8;
            unsigned* dst = smem + NWORDC;
            for (int i = tid; i < NWORD8; i += 1024) dst[i] = src[i];
        }
        __syncthreads();
        const int4* __restrict__ src4 = (const int4*)eb + (size_t)chunk * EPC4;
        const int4* __restrict__ dst4 = (const int4*)(eb + N_EDGES) + (size_t)chunk * EPC4;
        for (int i = tid; i < EPC4; i += 1024) {
            const int4 s4 = src4[i];
            const int4 d4 = dst4[i];
            const unsigned q0 = qs[d4.x];
            const unsigned q1 = qs[d4.y];
            const unsigned q2 = qs[d4.z];
            const unsigned q3 = qs[d4.w];
            atomicAdd(&cs[((unsigned)s4.x) >> 1], q0 << ((s4.x & 1) << 4));
            atomicAdd(&cs[((unsigned)s4.y) >> 1], q1 << ((s4.y & 1) << 4));
            atomicAdd(&cs[((unsigned)s4.z) >> 1], q2 << ((s4.z & 1) << 4));
            atomicAdd(&cs[((unsigned)s4.w) >> 1], q3 << ((s4.w & 1) << 4));
        }
        __syncthreads();
        unsigned* __restrict__ o = cpart + (size_t)(b * CHUNKS + chunk) * NWORDC;
        for (int i = tid; i < NWORDC; i += 1024) o[i] = cs[i];
    }
    __threadfence();
    grid.sync();

    // ---------------- Phase D: w (in LDS) + pool ----------------
    {
        float* wlds = (float*)smem;                 // [0, 6250) floats
        float* sacc = (float*)smem + 6272;          // 10 waves x 10 ch
        const int nc = chunk;                       // node-chunk for this block
        for (int i = tid; i < NODESPC / 2; i += 1024) {   // 3125 u32 words
            const unsigned* __restrict__ p =
                cpart + (size_t)(b * CHUNKS) * NWORDC + nc * (NODESPC / 2) + i;
            unsigned c0 = 0, c1 = 0;
#pragma unroll
            for (int c = 0; c < CHUNKS; ++c) {
                const unsigned v = p[(size_t)c * NWORDC];
                c0 += v & 0xFFFF; c1 += v >> 16;
            }
            const float2 d =
                *((const float2*)(dinv + (size_t)b * N_NODES + nc * NODESPC + 2 * i));
            wlds[2 * i]     = d.x * ((float)c0 * (1.0f / QSCALE) + d.x);
            wlds[2 * i + 1] = d.y * ((float)c1 * (1.0f / QSCALE) + d.y);
        }
        if (tid < 100) sacc[tid] = 0.0f;
        __syncthreads();

        float a0 = 0.0f, a1 = 0.0f, a2 = 0.0f, a3 = 0.0f;
        const int r = (4 * tid) % 10;   // const per lane for tid<640 (640*4%10==0)
        if (tid < 640) {
            const float4* __restrict__ xg4 = (const float4*)gcn_x;
            const int base4 = b * 125000 + nc * 15625;   // 4*base4 % 10 == 0
            const int nbase = b * N_NODES + nc * NODESPC;
            for (int j = tid; j < 15625; j += 640) {
                const int f4 = base4 + j;
                const int e0 = f4 * 4;
                const float4 v = xg4[f4];
                const int nl = e0 / 10 - nbase;          // local node idx in wlds
                const float w0 = wlds[nl];
                const float w1 = (r == 8) ? wlds[nl + 1] : w0;
                a0 += v.x * w0;
                a1 += v.y * w0;
                a2 += v.z * w1;
                a3 += v.w * w1;
            }
        }
        __syncthreads();
        if (tid < 640) {
            const int wave = tid >> 6;
            atomicAdd(&sacc[wave * 10 + r], a0);
            atomicAdd(&sacc[wave * 10 + (r + 1) % 10], a1);
            atomicAdd(&sacc[wave * 10 + (r + 2) % 10], a2);
            atomicAdd(&sacc[wave * 10 + (r + 3) % 10], a3);
        }
        __syncthreads();
        if (tid < 10) {
            float v = 0.0f;
#pragma unroll
            for (int wv = 0; wv < 10; ++wv) v += sacc[wv * 10 + tid];
            spart[(b * CHUNKS + nc) * 16 + tid] = v;
        }
    }
    __threadfence();
    grid.sync();

    // ---------------- Phase E: MLP + log_softmax (block 0) ----------------
    if (id != 0) return;
    {
        float* ssum = (float*)smem;        // 32*10
        float* h0   = ssum + 320;          // 32*20
        float* h1   = h0 + 640;            // 32*80
        float* h2   = h1 + 2560;           // 32*160
        float* o    = h2 + 5120;           // 32*4

        for (int idx = tid; idx < 32 * 10; idx += 1024) {
            const int bb = idx / 10, k = idx % 10;
            float v = 0.0f;
#pragma unroll
            for (int c = 0; c < CHUNKS; ++c) v += spart[(bb * CHUNKS + c) * 16 + k];
            ssum[bb * 10 + k] = v;
        }
        __syncthreads();

        for (int idx = tid; idx < 32 * 20; idx += 1024) {
            const int bb = idx / 20, j = idx % 20;
            float v;
            if (j < 10) {
                v = 0.0f;
#pragma unroll
                for (int k = 0; k < 10; ++k) v += ssum[bb * 10 + k] * W_gcn[k * 10 + j];
                v = v * (1.0f / (float)N_NODES) + b_gcn[j];
            } else {
                v = x[bb * 10 + (j - 10)];
            }
            h0[bb * 20 + j] = v;
        }
        __syncthreads();

        for (int idx = tid; idx < 32 * 80; idx += 1024) {
            const int bb = idx / 80, j = idx % 80;
            float v = b1[j];
#pragma unroll
            for (int k = 0; k < 20; ++k) v += h0[bb * 20 + k] * W1[k * 80 + j];
            h1[bb * 80 + j] = (v > 0.0f) ? v : 0.01f * v;
        }
        __syncthreads();

        for (int idx = tid; idx < 32 * 160; idx += 1024) {
            const int bb = idx / 160, j = idx % 160;
            float v = b2[j];
            for (int k = 0; k < 80; ++k) v += h1[bb * 80 + k] * W2[k * 160 + j];
            h2[bb * 160 + j] = (v > 0.0f) ? v : 0.01f * v;
        }
        __syncthreads();

        for (int idx = tid; idx < 32 * 4; idx += 1024) {
            const int bb = idx / 4, j = idx % 4;
            float v = bo[j];
            for (int k = 0; k < 160; ++k) v += h2[bb * 160 + k] * Wo[k * 4 + j];
            o[bb * 4 + j] = v;
        }
        __syncthreads();

        if (tid < 4) {
            float m = -1e30f;
            for (int bb = 0; bb < 32; ++bb) m = fmaxf(m, o[bb * 4 + tid]);
            float lse = 0.0f;
            for (int bb = 0; bb < 32; ++bb) lse += expf(o[bb * 4 + tid] - m);
            lse = logf(lse);
            for (int bb = 0; bb < 32; ++bb) out[bb * 4 + tid] = o[bb * 4 + tid] - m - lse;
        }
    }
}

extern "C" void kernel_launch(void* const* d_in, const int* in_sizes, int n_in,
                              void* d_out, int out_size, void* d_ws, size_t ws_size,
                              hipStream_t stream) {
    const float* x      = (const float*)d_in[0];
    const float* gcn_x  = (const float*)d_in[1];
    const int*   ei     = (const int*)d_in[2];
    const float* W_gcn  = (const float*)d_in[3];
    const float* b_gcn  = (const float*)d_in[4];
    const float* W1     = (const float*)d_in[5];
    const float* b1     = (const float*)d_in[6];
    const float* W2     = (const float*)d_in[7];
    const float* b2     = (const float*)d_in[8];
    const float* Wo     = (const float*)d_in[9];
    const float* bo     = (const float*)d_in[10];
    float* out = (float*)d_out;

    // workspace layout (bytes):
    //   hpart [32*8*12500 u32] @ 0           (12.8 MB)
    //   cpart [32*8*25000 u32] @ 12,800,000  (25.6 MB)
    //   dinv  [32*50000 f32]   @ 38,400,000  (6.4 MB)
    //   qd8   [32*12500 u32]   @ 44,800,000  (1.6 MB)
    //   spart [32*8*16 f32]    @ 46,400,000  (16 KB)   total ~46.4 MB
    unsigned* hpart = (unsigned*)d_ws;
    unsigned* cpart = (unsigned*)((char*)d_ws + (size_t)BATCH * CHUNKS * NWORD8 * 4);
    float*    dinv  = (float*)((char*)cpart + (size_t)BATCH * CHUNKS * NWORDC * 4);
    unsigned* qd8   = (unsigned*)((char*)dinv + (size_t)BATCH * N_NODES * 4);
    float*    spart = (float*)((char*)qd8 + (size_t)BATCH * NWORD8 * 4);

    hipFuncSetAttribute((const void*)mega_kernel,
                        hipFuncAttributeMaxDynamicSharedMemorySize, SMEM_WORDS * 4);

    void* args[] = {
        (void*)&x, (void*)&gcn_x, (void*)&ei,
        (void*)&W_gcn, (void*)&b_gcn,
        (void*)&W1, (void*)&b1, (void*)&W2, (void*)&b2,
        (void*)&Wo, (void*)&bo, (void*)&out,
        (void*)&hpart, (void*)&cpart, (void*)&dinv, (void*)&qd8, (void*)&spart,
    };
    hipLaunchCooperativeKernel((const void*)mega_kernel, dim3(256), dim3(1024),
                               args, SMEM_WORDS * 4, stream);
}